// Round 11
// baseline (5725.264 us; speedup 1.0000x reference)
//
#include <hip/hip_runtime.h>
#include <hip/hip_bf16.h>

typedef __bf16 bf16x8 __attribute__((ext_vector_type(8)));
typedef float f32x4 __attribute__((ext_vector_type(4)));
typedef unsigned short u16;

#define GLD_LDS16(gp, lp) __builtin_amdgcn_global_load_lds( \
    (const __attribute__((address_space(1))) unsigned int*)(gp), \
    (__attribute__((address_space(3))) unsigned int*)(lp), 16, 0, 0)

__device__ __forceinline__ float tanh_fast(float x) {
  float e = __expf(2.0f * x);
  return 1.0f - __fdividef(2.0f, e + 1.0f);
}

__device__ __forceinline__ u16 bf16_rn(float x) {
  union { float f; unsigned u; } v; v.f = x;
  unsigned r = v.u + 0x7fffu + ((v.u >> 16) & 1u);
  return (u16)(r >> 16);
}

// ---------------------------------------------------------------------------
// Fused GEMM: C[M,N] = A[M,K] (bf16 row-major) x Bt[N,K]^T (bf16 row-major)
// R11 = R8 (T2 both-sides XOR swizzle + XCD m-band swizzle + direct fragment
// epilogue) with minimum-2-phase prefetch (T3 recipe):
//   prologue: stage(buf0, t=0); __syncthreads;
//   for t: [stage(buf[t+1 &1], t+1)] ; ds_read+MFMA from buf[t&1] ;
//          __syncthreads  (its vmcnt(0) lands AFTER compute -> stage hidden)
// Buffers are STATICALLY indexed via full unroll (constexpr NT) so the
// compiler can disambiguate in-flight global_load_lds (buf^1) from ds_read
// (buf cur) and does NOT insert a drain before the reads -- the diagnosed
// failure mode of the R2/R7 dynamic-index attempts.
// 2 buffers fit 64KB (2 blocks/CU kept): GEMM-A BK=64, GEMM-B BK=128.
// MODE 0: out_bf = bf16(tanh(acc + bias + t*wt))
// MODE 1: v = 0.999*y + 0.001*z + h*(acc+bias); out32 = v; out_bf = v
// MODE 2: v = z + h*(acc+bias);                 out32 = v; out_bf = v
// ---------------------------------------------------------------------------
template <int BM, int BN, int BK, int K, int MODE, int NTL>
__global__ __launch_bounds__(256)
void gemm_fused(const u16* __restrict__ A, const u16* __restrict__ Bt,
                const float* __restrict__ bias, const float* __restrict__ wt,
                float tval,
                const float* __restrict__ y_in, const float* __restrict__ z_in,
                float* __restrict__ out32, u16* __restrict__ out_bf, int N) {
  constexpr int NS = BK / 64;                 // 64-col slabs per K-tile
  constexpr int WTM = BM / 2, WTN = BN / 2;   // per-wave tile (2x2 wave grid)
  constexpr int FM = WTM / 16, FN = WTN / 16; // fragments per wave
  constexpr int ACH = BM * BK * 2 / 1024;     // 1KB staging chunks
  constexpr int BCH = BN * BK * 2 / 1024;
  constexpr int CPS_A = BM / 8;               // chunks per slab
  constexpr int CPS_B = BN / 8;
  constexpr int MT = 4096 / BM;               // m-tiles total
  constexpr int MPX = MT / 8;                 // m-tiles per XCD
  constexpr int NT = K / BK;                  // K-tiles
  static_assert(NT >= 2, "need >=2 K-tiles");

  __shared__ u16 As[2][NS * BM * 64];  // [buf][slab][row][64]
  __shared__ u16 Bs[2][NS * BN * 64];

  const int tid = threadIdx.x;
  const int wave = tid >> 6;
  const int lane = tid & 63;
  const int wm = wave >> 1, wn = wave & 1;
  const int l15 = lane & 15, kg = lane >> 4;

  const int wg = blockIdx.x;
  const int xcd = wg & 7;
  const int j = wg >> 3;
  const int bm0 = (xcd * MPX + j / NTL) * BM;
  const int bn0 = (j % NTL) * BN;

  f32x4 acc[FM][FN];
#pragma unroll
  for (int m = 0; m < FM; ++m)
#pragma unroll
    for (int n = 0; n < FN; ++n) acc[m][n] = (f32x4){0.f, 0.f, 0.f, 0.f};

  const int sr = lane >> 3;                     // row within 8-row (1KB) chunk
  const int scs = ((lane & 7) ^ sr) * 8;        // PRE-SWIZZLED src col
  const int rsw = (l15 & 7) << 3;               // read-side XOR

  const u16* Ag = A + (size_t)bm0 * K;
  const u16* Bg = Bt + (size_t)bn0 * K;

  auto stage = [&](int buf, int kt) {
    const u16* Ak = Ag + (size_t)kt * BK;
    const u16* Bk = Bg + (size_t)kt * BK;
#pragma unroll
    for (int i = 0; i < ACH / 4; ++i) {
      const int ch = wave + i * 4;
      const int kh = ch / CPS_A;
      const int rg = ch % CPS_A;
      GLD_LDS16(Ak + (size_t)(rg * 8 + sr) * K + kh * 64 + scs,
                (char*)As[buf] + ch * 1024);
    }
#pragma unroll
    for (int i = 0; i < BCH / 4; ++i) {
      const int ch = wave + i * 4;
      const int kh = ch / CPS_B;
      const int rg = ch % CPS_B;
      GLD_LDS16(Bk + (size_t)(rg * 8 + sr) * K + kh * 64 + scs,
                (char*)Bs[buf] + ch * 1024);
    }
  };

  stage(0, 0);
  __syncthreads();  // one exposed drain for tile 0 (prologue only)

#pragma unroll
  for (int kt = 0; kt < NT; ++kt) {
    if (kt + 1 < NT) stage((kt + 1) & 1, kt + 1);  // in flight under compute
    const u16* Asl = As[kt & 1];
    const u16* Bsl = Bs[kt & 1];
#pragma unroll
    for (int ks = 0; ks < 2 * NS; ++ks) {
      const int kh = ks >> 1;
      const int kc = ((ks & 1) * 32 + kg * 8) ^ rsw;  // swizzled read col
      bf16x8 af[FM], bfr[FN];
#pragma unroll
      for (int m = 0; m < FM; ++m)
        af[m] = *reinterpret_cast<const bf16x8*>(
            &Asl[(kh * BM + wm * WTM + m * 16 + l15) * 64 + kc]);
#pragma unroll
      for (int n = 0; n < FN; ++n)
        bfr[n] = *reinterpret_cast<const bf16x8*>(
            &Bsl[(kh * BN + wn * WTN + n * 16 + l15) * 64 + kc]);
#pragma unroll
      for (int m = 0; m < FM; ++m)
#pragma unroll
        for (int n = 0; n < FN; ++n)
          acc[m][n] =
              __builtin_amdgcn_mfma_f32_16x16x32_bf16(af[m], bfr[n], acc[m][n], 0, 0, 0);
    }
    // vmcnt(0)+lgkmcnt(0)+barrier: stage (hidden under the MFMAs above) has
    // landed; all waves done reading buf[kt&1] before it is re-staged.
    __syncthreads();
  }

  // Epilogue (R4 direct stores). C/D layout: col = lane&15, row = (lane>>4)*4 + reg.
#pragma unroll
  for (int n = 0; n < FN; ++n) {
    const int col = bn0 + wn * WTN + n * 16 + l15;
    const float bv = bias[col];
    const float wv = (MODE == 0) ? wt[col] : 0.f;
#pragma unroll
    for (int m = 0; m < FM; ++m) {
      const int row0 = bm0 + wm * WTM + m * 16 + kg * 4;
#pragma unroll
      for (int r = 0; r < 4; ++r) {
        const size_t idx = (size_t)(row0 + r) * N + col;
        const float a = acc[m][n][r];
        if (MODE == 0) {
          const float x = a + bv + tval * wv;
          out_bf[idx] = bf16_rn(tanh_fast(x));
        } else if (MODE == 1) {
          const float v = 0.999f * y_in[idx] + 0.001f * z_in[idx] +
                          0.015625f * (a + bv);
          out32[idx] = v;
          out_bf[idx] = bf16_rn(v);
        } else {
          const float v = z_in[idx] + 0.015625f * (a + bv);
          out32[idx] = v;
          out_bf[idx] = bf16_rn(v);
        }
      }
    }
  }
}

// in: [R, C] f32  ->  out: [C, R] bf16
__global__ void transpose_bf16(const float* __restrict__ in, u16* __restrict__ out,
                               int R, int C) {
  __shared__ float tile[32][33];
  const int bx = blockIdx.x * 32;
  const int by = blockIdx.y * 32;
  const int tx = threadIdx.x, ty = threadIdx.y;  // 32 x 8
#pragma unroll
  for (int i = 0; i < 32; i += 8)
    tile[ty + i][tx] = in[(size_t)(by + ty + i) * C + (bx + tx)];
  __syncthreads();
#pragma unroll
  for (int i = 0; i < 32; i += 8)
    out[(size_t)(bx + ty + i) * R + (by + tx)] = bf16_rn(tile[tx][ty + i]);
}

__global__ void init_state(const float* __restrict__ y0, float* __restrict__ y32,
                           float* __restrict__ z32, u16* __restrict__ zbf, int n) {
  const int i = blockIdx.x * blockDim.x + threadIdx.x;
  if (i < n) {
    const float v = y0[i];
    y32[i] = v;
    z32[i] = v;
    zbf[i] = bf16_rn(v);
  }
}

extern "C" void kernel_launch(void* const* d_in, const int* in_sizes, int n_in,
                              void* d_out, int out_size, void* d_ws, size_t ws_size,
                              hipStream_t stream) {
  const float* y0 = (const float*)d_in[0];
  const float* W1 = (const float*)d_in[1];  // [512, 2048]
  const float* b1 = (const float*)d_in[2];  // [2048]
  const float* wt = (const float*)d_in[3];  // [2048]
  const float* W2 = (const float*)d_in[4];  // [2048, 512]
  const float* b2 = (const float*)d_in[5];  // [512]

  constexpr int B = 4096, D = 512, HID = 2048, NSTEP = 64;
  constexpr float Hh = 1.0f / 64.0f;

  char* ws = (char*)d_ws;
  u16* W1t = (u16*)ws; ws += (size_t)HID * D * 2;   // [2048][512] bf16
  u16* W2t = (u16*)ws; ws += (size_t)D * HID * 2;   // [512][2048] bf16
  u16* hid = (u16*)ws; ws += (size_t)B * HID * 2;   // [4096][2048] bf16
  float* z32 = (float*)ws; ws += (size_t)B * D * 4; // [4096][512] f32
  u16* ybf = (u16*)ws; ws += (size_t)B * D * 2;
  u16* zbf = (u16*)ws; ws += (size_t)B * D * 2;
  float* y32 = (float*)d_out;

  transpose_bf16<<<dim3(HID / 32, D / 32), dim3(32, 8), 0, stream>>>(W1, W1t, D, HID);
  transpose_bf16<<<dim3(D / 32, HID / 32), dim3(32, 8), 0, stream>>>(W2, W2t, HID, D);
  init_state<<<(B * D + 255) / 256, 256, 0, stream>>>(y0, y32, z32, zbf, B * D);

  for (int s = 0; s < NSTEP; ++s) {
    const float t0 = (float)s * Hh;
    const float t1 = (float)(s + 1) * Hh;
    // hidden = tanh(z @ W1 + b1 + t0*wt)   512 blocks (32 m-tiles x 16 n-tiles)
    gemm_fused<128, 128, 64, 512, 0, 16><<<512, 256, 0, stream>>>(
        zbf, W1t, b1, wt, t0, nullptr, nullptr, nullptr, hid, HID);
    // y = 0.999*y + 0.001*z + h*(hidden @ W2 + b2)   512 blocks (64 x 8)
    gemm_fused<64, 64, 128, 2048, 1, 8><<<512, 256, 0, stream>>>(
        hid, W2t, b2, nullptr, 0.f, y32, z32, y32, ybf, D);
    // hidden = tanh(y @ W1 + b1 + t1*wt)
    gemm_fused<128, 128, 64, 512, 0, 16><<<512, 256, 0, stream>>>(
        ybf, W1t, b1, wt, t1, nullptr, nullptr, nullptr, hid, HID);
    // z = z + h*(hidden @ W2 + b2)
    gemm_fused<64, 64, 128, 2048, 2, 8><<<512, 256, 0, stream>>>(
        hid, W2t, b2, nullptr, 0.f, nullptr, z32, z32, zbf, D);
  }
}

// Round 12
// 4206.697 us; speedup vs baseline: 1.3610x; 1.3610x over previous
//
#include <hip/hip_runtime.h>
#include <hip/hip_bf16.h>

typedef __bf16 bf16x8 __attribute__((ext_vector_type(8)));
typedef float f32x4 __attribute__((ext_vector_type(4)));
typedef unsigned short u16;

#define GLD_LDS16(gp, lp) __builtin_amdgcn_global_load_lds( \
    (const __attribute__((address_space(1))) unsigned int*)(gp), \
    (__attribute__((address_space(3))) unsigned int*)(lp), 16, 0, 0)

__device__ __forceinline__ float tanh_fast(float x) {
  float e = __expf(2.0f * x);
  return 1.0f - __fdividef(2.0f, e + 1.0f);
}

__device__ __forceinline__ u16 bf16_rn(float x) {
  union { float f; unsigned u; } v; v.f = x;
  unsigned r = v.u + 0x7fffu + ((v.u >> 16) & 1u);
  return (u16)(r >> 16);
}

// ---------------------------------------------------------------------------
// Fused GEMM: C[M,N] = A[M,K] (bf16 row-major) x Bt[N,K]^T (bf16 row-major)
// R12 = R8 (proven best: single-buffer 2-barrier loop, 64-col LDS slabs,
// T2 both-sides XOR swizzle, XCD m-band swizzle, direct fragment epilogue;
// GEMM-A 128x128 BK=128, GEMM-B 64x64 BK=256, both grid 512 = 2 blocks/CU)
// + residual micro-bundle:
//   (1) s_setprio(1) around each MFMA cluster (T5)
//   (2) __launch_bounds__(256, 2) regalloc hint (8 waves/CU actual)
//   (3) A/B staging chunks interleaved (spread L2 pressure in the drain)
//   (4) epilogue y/z loads hoisted ahead of arithmetic
// Pipelining is structurally closed on this LDS budget (R2/R7/R11: dbuf
// forces BK-halving or occupancy loss; __syncthreads drains vmcnt(0)).
// MODE 0: out_bf = bf16(tanh(acc + bias + t*wt))
// MODE 1: v = 0.999*y + 0.001*z + h*(acc+bias); out32 = v; out_bf = v
// MODE 2: v = z + h*(acc+bias);                 out32 = v; out_bf = v
// ---------------------------------------------------------------------------
template <int BM, int BN, int BK, int K, int MODE, int NTL>
__global__ __launch_bounds__(256, 2)
void gemm_fused(const u16* __restrict__ A, const u16* __restrict__ Bt,
                const float* __restrict__ bias, const float* __restrict__ wt,
                float tval,
                const float* __restrict__ y_in, const float* __restrict__ z_in,
                float* __restrict__ out32, u16* __restrict__ out_bf, int N) {
  constexpr int NS = BK / 64;                 // 64-col slabs
  constexpr int WTM = BM / 2, WTN = BN / 2;   // per-wave tile (2x2 wave grid)
  constexpr int FM = WTM / 16, FN = WTN / 16; // fragments per wave
  constexpr int ACH = BM * BK * 2 / 1024;     // 1KB staging chunks
  constexpr int BCH = BN * BK * 2 / 1024;
  constexpr int CPS_A = BM / 8;               // chunks per slab
  constexpr int CPS_B = BN / 8;
  constexpr int MT = 4096 / BM;               // m-tiles total
  constexpr int MPX = MT / 8;                 // m-tiles per XCD
  constexpr int NCH = ACH / 4;                // per-wave A chunks (== B chunks)
  static_assert(ACH / 4 == BCH / 4 || true, "");

  __shared__ u16 As[NS * BM * 64];  // [slab][row][64]
  __shared__ u16 Bs[NS * BN * 64];

  const int tid = threadIdx.x;
  const int wave = tid >> 6;
  const int lane = tid & 63;
  const int wm = wave >> 1, wn = wave & 1;
  const int l15 = lane & 15, kg = lane >> 4;

  const int wg = blockIdx.x;
  const int xcd = wg & 7;
  const int j = wg >> 3;
  const int bm0 = (xcd * MPX + j / NTL) * BM;
  const int bn0 = (j % NTL) * BN;

  f32x4 acc[FM][FN];
#pragma unroll
  for (int m = 0; m < FM; ++m)
#pragma unroll
    for (int n = 0; n < FN; ++n) acc[m][n] = (f32x4){0.f, 0.f, 0.f, 0.f};

  const int sr = lane >> 3;                     // row within 8-row (1KB) chunk
  const int scs = ((lane & 7) ^ sr) * 8;        // PRE-SWIZZLED src col
  const int rsw = (l15 & 7) << 3;               // read-side XOR

  const u16* Ag = A + (size_t)bm0 * K;
  const u16* Bg = Bt + (size_t)bn0 * K;

  for (int kt = 0; kt < K / BK; ++kt) {
    const u16* Ak = Ag + kt * BK;
    const u16* Bk = Bg + kt * BK;
    // Interleaved A/B chunk issue (bundle item 3).
#pragma unroll
    for (int i = 0; i < NCH; ++i) {
      {
        const int ch = wave + i * 4;
        const int kh = ch / CPS_A;
        const int rg = ch % CPS_A;
        GLD_LDS16(Ak + (size_t)(rg * 8 + sr) * K + kh * 64 + scs,
                  (char*)As + ch * 1024);
      }
      if (i < BCH / 4) {
        const int ch = wave + i * 4;
        const int kh = ch / CPS_B;
        const int rg = ch % CPS_B;
        GLD_LDS16(Bk + (size_t)(rg * 8 + sr) * K + kh * 64 + scs,
                  (char*)Bs + ch * 1024);
      }
    }
    __syncthreads();
#pragma unroll
    for (int ks = 0; ks < 2 * NS; ++ks) {
      const int kh = ks >> 1;
      const int kc = ((ks & 1) * 32 + kg * 8) ^ rsw;  // swizzled read col
      bf16x8 af[FM], bfr[FN];
#pragma unroll
      for (int m = 0; m < FM; ++m)
        af[m] = *reinterpret_cast<const bf16x8*>(
            &As[(kh * BM + wm * WTM + m * 16 + l15) * 64 + kc]);
#pragma unroll
      for (int n = 0; n < FN; ++n)
        bfr[n] = *reinterpret_cast<const bf16x8*>(
            &Bs[(kh * BN + wn * WTN + n * 16 + l15) * 64 + kc]);
      __builtin_amdgcn_s_setprio(1);  // T5: favor MFMA cluster
#pragma unroll
      for (int m = 0; m < FM; ++m)
#pragma unroll
        for (int n = 0; n < FN; ++n)
          acc[m][n] =
              __builtin_amdgcn_mfma_f32_16x16x32_bf16(af[m], bfr[n], acc[m][n], 0, 0, 0);
      __builtin_amdgcn_s_setprio(0);
    }
    __syncthreads();
  }

  // Epilogue (R4 direct stores). C/D layout: col = lane&15, row = (lane>>4)*4 + reg.
#pragma unroll
  for (int n = 0; n < FN; ++n) {
    const int col = bn0 + wn * WTN + n * 16 + l15;
    const float bv = bias[col];
    const float wv = (MODE == 0) ? wt[col] : 0.f;
#pragma unroll
    for (int m = 0; m < FM; ++m) {
      const int row0 = bm0 + wm * WTM + m * 16 + kg * 4;
      if (MODE == 0) {
#pragma unroll
        for (int r = 0; r < 4; ++r) {
          const size_t idx = (size_t)(row0 + r) * N + col;
          const float x = acc[m][n][r] + bv + tval * wv;
          out_bf[idx] = bf16_rn(tanh_fast(x));
        }
      } else {
        // Hoist y/z loads ahead of arithmetic (bundle item 4).
        float yv[4], zv[4];
#pragma unroll
        for (int r = 0; r < 4; ++r) {
          const size_t idx = (size_t)(row0 + r) * N + col;
          zv[r] = z_in[idx];
          if (MODE == 1) yv[r] = y_in[idx];
        }
#pragma unroll
        for (int r = 0; r < 4; ++r) {
          const size_t idx = (size_t)(row0 + r) * N + col;
          const float a = acc[m][n][r] + bv;
          const float v = (MODE == 1)
              ? 0.999f * yv[r] + 0.001f * zv[r] + 0.015625f * a
              : zv[r] + 0.015625f * a;
          out32[idx] = v;
          out_bf[idx] = bf16_rn(v);
        }
      }
    }
  }
}

// in: [R, C] f32  ->  out: [C, R] bf16
__global__ void transpose_bf16(const float* __restrict__ in, u16* __restrict__ out,
                               int R, int C) {
  __shared__ float tile[32][33];
  const int bx = blockIdx.x * 32;
  const int by = blockIdx.y * 32;
  const int tx = threadIdx.x, ty = threadIdx.y;  // 32 x 8
#pragma unroll
  for (int i = 0; i < 32; i += 8)
    tile[ty + i][tx] = in[(size_t)(by + ty + i) * C + (bx + tx)];
  __syncthreads();
#pragma unroll
  for (int i = 0; i < 32; i += 8)
    out[(size_t)(bx + ty + i) * R + (by + tx)] = bf16_rn(tile[tx][ty + i]);
}

__global__ void init_state(const float* __restrict__ y0, float* __restrict__ y32,
                           float* __restrict__ z32, u16* __restrict__ zbf, int n) {
  const int i = blockIdx.x * blockDim.x + threadIdx.x;
  if (i < n) {
    const float v = y0[i];
    y32[i] = v;
    z32[i] = v;
    zbf[i] = bf16_rn(v);
  }
}

extern "C" void kernel_launch(void* const* d_in, const int* in_sizes, int n_in,
                              void* d_out, int out_size, void* d_ws, size_t ws_size,
                              hipStream_t stream) {
  const float* y0 = (const float*)d_in[0];
  const float* W1 = (const float*)d_in[1];  // [512, 2048]
  const float* b1 = (const float*)d_in[2];  // [2048]
  const float* wt = (const float*)d_in[3];  // [2048]
  const float* W2 = (const float*)d_in[4];  // [2048, 512]
  const float* b2 = (const float*)d_in[5];  // [512]

  constexpr int B = 4096, D = 512, HID = 2048, NSTEP = 64;
  constexpr float Hh = 1.0f / 64.0f;

  char* ws = (char*)d_ws;
  u16* W1t = (u16*)ws; ws += (size_t)HID * D * 2;   // [2048][512] bf16
  u16* W2t = (u16*)ws; ws += (size_t)D * HID * 2;   // [512][2048] bf16
  u16* hid = (u16*)ws; ws += (size_t)B * HID * 2;   // [4096][2048] bf16
  float* z32 = (float*)ws; ws += (size_t)B * D * 4; // [4096][512] f32
  u16* ybf = (u16*)ws; ws += (size_t)B * D * 2;
  u16* zbf = (u16*)ws; ws += (size_t)B * D * 2;
  float* y32 = (float*)d_out;

  transpose_bf16<<<dim3(HID / 32, D / 32), dim3(32, 8), 0, stream>>>(W1, W1t, D, HID);
  transpose_bf16<<<dim3(D / 32, HID / 32), dim3(32, 8), 0, stream>>>(W2, W2t, HID, D);
  init_state<<<(B * D + 255) / 256, 256, 0, stream>>>(y0, y32, z32, zbf, B * D);

  for (int s = 0; s < NSTEP; ++s) {
    const float t0 = (float)s * Hh;
    const float t1 = (float)(s + 1) * Hh;
    // hidden = tanh(z @ W1 + b1 + t0*wt)   512 blocks (32 m-tiles x 16 n-tiles)
    gemm_fused<128, 128, 128, 512, 0, 16><<<512, 256, 0, stream>>>(
        zbf, W1t, b1, wt, t0, nullptr, nullptr, nullptr, hid, HID);
    // y = 0.999*y + 0.001*z + h*(hidden @ W2 + b2)   512 blocks (64 x 8)
    gemm_fused<64, 64, 256, 2048, 1, 8><<<512, 256, 0, stream>>>(
        hid, W2t, b2, nullptr, 0.f, y32, z32, y32, ybf, D);
    // hidden = tanh(y @ W1 + b1 + t1*wt)
    gemm_fused<128, 128, 128, 512, 0, 16><<<512, 256, 0, stream>>>(
        ybf, W1t, b1, wt, t1, nullptr, nullptr, nullptr, hid, HID);
    // z = z + h*(hidden @ W2 + b2)
    gemm_fused<64, 64, 256, 2048, 2, 8><<<512, 256, 0, stream>>>(
        hid, W2t, b2, nullptr, 0.f, nullptr, z32, z32, zbf, D);
  }
}